// Round 1
// baseline (472.513 us; speedup 1.0000x reference)
//
#include <hip/hip_runtime.h>
#include <hip/hip_bf16.h>

#define N 4096
#define C 512

typedef __attribute__((ext_vector_type(8))) short bf16x8;
typedef __attribute__((ext_vector_type(4))) float f32x4;

__device__ inline float bf2f(__hip_bfloat16 h) { return __bfloat162float(h); }

__device__ inline void gload16(const void* g, void* l) {
    __builtin_amdgcn_global_load_lds(
        (__attribute__((address_space(1))) void*)(g),
        (__attribute__((address_space(3))) void*)(l),
        16, 0, 0);
}

// ---------------- kernel 1: row L2-normalize + bf16 hi/lo split ----------------
__global__ __launch_bounds__(256) void k_norm_split(
    const float* __restrict__ src,
    __hip_bfloat16* __restrict__ hi, __hip_bfloat16* __restrict__ lo)
{
    const int row = blockIdx.x;
    const int tid = threadIdx.x;
    const float2* r = (const float2*)(src + (size_t)row * C);
    float2 x = r[tid];                       // 256 threads * 2 = 512
    float ss = x.x * x.x + x.y * x.y;
    for (int o = 1; o < 64; o <<= 1) ss += __shfl_xor(ss, o);
    __shared__ float wsum[4];
    if ((tid & 63) == 0) wsum[tid >> 6] = ss;
    __syncthreads();
    float tot = wsum[0] + wsum[1] + wsum[2] + wsum[3];
    float nrm = sqrtf(tot);
    float scale = 1.0f / fmaxf(nrm, 1e-12f);
    float y0 = x.x * scale, y1 = x.y * scale;
    __hip_bfloat16 h0 = __float2bfloat16(y0);
    __hip_bfloat16 h1 = __float2bfloat16(y1);
    __hip_bfloat16 l0 = __float2bfloat16(y0 - bf2f(h0));
    __hip_bfloat16 l1 = __float2bfloat16(y1 - bf2f(h1));
    size_t base = (size_t)row * C + 2 * tid;
    hi[base] = h0; hi[base + 1] = h1;
    lo[base] = l0; lo[base + 1] = l1;
}

// ---------------- kernel 2: diagonal dots (split arithmetic) ----------------
__global__ __launch_bounds__(256) void k_diag(
    const __hip_bfloat16* __restrict__ ah, const __hip_bfloat16* __restrict__ al,
    const __hip_bfloat16* __restrict__ bh, const __hip_bfloat16* __restrict__ bl,
    float* __restrict__ dout)
{
    const int lane = threadIdx.x & 63;
    const int w = threadIdx.x >> 6;
    const int row = blockIdx.x * 4 + w;
    size_t base = (size_t)row * C;
    float s = 0.f;
    for (int j = lane; j < C; j += 64) {
        float xh = bf2f(ah[base + j]), xl = bf2f(al[base + j]);
        float yh = bf2f(bh[base + j]), yl = bf2f(bl[base + j]);
        s += xh * yh + xh * yl + xl * yh;
    }
    for (int o = 1; o < 64; o <<= 1) s += __shfl_xor(s, o);
    if (lane == 0) dout[row] = s;
}

// ---------------- kernel 3: fused split-GEMM + epilogue ----------------
// C-tile 128x128, BK=32, 4 waves (2x2), 3 MFMA per frag pair (hi*hi+hi*lo+lo*hi).
// Epilogue: per-row sum of exp(10s-10) and count(s > diag, col!=row),
// written as partials [colblock][row].
__global__ __launch_bounds__(256) void k_gemm(
    const __hip_bfloat16* __restrict__ Ah, const __hip_bfloat16* __restrict__ Al,
    const __hip_bfloat16* __restrict__ Bh, const __hip_bfloat16* __restrict__ Bl,
    const float* __restrict__ diag,
    float* __restrict__ pe, float* __restrict__ pc)
{
    __shared__ __align__(16) __hip_bfloat16 sA[2][128][32];
    __shared__ __align__(16) __hip_bfloat16 sB[2][128][32];
    __shared__ float sdiag[128];
    __shared__ float sred[128][2][2];

    const int tid = threadIdx.x;
    const int lane = tid & 63;
    const int w = tid >> 6;
    const int wy = w >> 1, wx = w & 1;
    const int bm = blockIdx.x * 128;
    const int bn = blockIdx.y * 128;

    if (tid < 128) sdiag[tid] = diag[bm + tid];

    f32x4 acc[4][4];
    for (int i = 0; i < 4; i++)
        for (int j = 0; j < 4; j++)
            acc[i][j] = (f32x4){0.f, 0.f, 0.f, 0.f};

    const int srow = lane >> 2;        // 0..15
    const int scol = (lane & 3) * 8;   // bf16 elems
    const int fr = lane & 15;
    const int fq = (lane >> 4) * 8;

    for (int k0 = 0; k0 < C; k0 += 32) {
        // stage 4 tiles: A hi/lo (rows bm..), B hi/lo (rows bn..)
        for (int half = 0; half < 2; half++) {
            int rr = w * 16 + half * 64 + srow;
            size_t ga = (size_t)(bm + rr) * C + k0 + scol;
            size_t gb = (size_t)(bn + rr) * C + k0 + scol;
            gload16(Ah + ga, &sA[0][rr][scol]);
            gload16(Al + ga, &sA[1][rr][scol]);
            gload16(Bh + gb, &sB[0][rr][scol]);
            gload16(Bl + gb, &sB[1][rr][scol]);
        }
        __syncthreads();

        bf16x8 a_h[4], a_l[4], b_h[4], b_l[4];
        for (int i = 0; i < 4; i++) {
            a_h[i] = *(const bf16x8*)&sA[0][wy * 64 + i * 16 + fr][fq];
            a_l[i] = *(const bf16x8*)&sA[1][wy * 64 + i * 16 + fr][fq];
            b_h[i] = *(const bf16x8*)&sB[0][wx * 64 + i * 16 + fr][fq];
            b_l[i] = *(const bf16x8*)&sB[1][wx * 64 + i * 16 + fr][fq];
        }
        for (int i = 0; i < 4; i++)
            for (int j = 0; j < 4; j++) {
                acc[i][j] = __builtin_amdgcn_mfma_f32_16x16x32_bf16(a_h[i], b_h[j], acc[i][j], 0, 0, 0);
                acc[i][j] = __builtin_amdgcn_mfma_f32_16x16x32_bf16(a_h[i], b_l[j], acc[i][j], 0, 0, 0);
                acc[i][j] = __builtin_amdgcn_mfma_f32_16x16x32_bf16(a_l[i], b_h[j], acc[i][j], 0, 0, 0);
            }
        __syncthreads();
    }

    // epilogue: C/D layout row=(lane>>4)*4+reg, col=lane&15
    const int quad = lane >> 4;
    for (int i = 0; i < 4; i++) {
        for (int reg = 0; reg < 4; reg++) {
            int rloc = wy * 64 + i * 16 + quad * 4 + reg;
            int grow = bm + rloc;
            float d = sdiag[rloc];
            float e = 0.f, c = 0.f;
            for (int j = 0; j < 4; j++) {
                float s = acc[i][j][reg];
                int gcol = bn + wx * 64 + j * 16 + fr;
                e += __expf(10.f * s - 10.f);
                if (s > d && gcol != grow) c += 1.f;
            }
            for (int o = 1; o < 16; o <<= 1) {
                e += __shfl_xor(e, o);
                c += __shfl_xor(c, o);
            }
            if (fr == 0) { sred[rloc][wx][0] = e; sred[rloc][wx][1] = c; }
        }
    }
    __syncthreads();
    if (tid < 128) {
        pe[(size_t)blockIdx.y * N + bm + tid] = sred[tid][0][0] + sred[tid][1][0];
        pc[(size_t)blockIdx.y * N + bm + tid] = sred[tid][0][1] + sred[tid][1][1];
    }
}

// ---------------- kernel 4: per-column sum / sumsq partials (512 rows/chunk) ----------------
__global__ __launch_bounds__(512) void k_stdp(
    const __hip_bfloat16* __restrict__ hi, const __hip_bfloat16* __restrict__ lo,
    float* __restrict__ s1, float* __restrict__ s2)
{
    const int col = threadIdx.x;
    const int chunk = blockIdx.x;
    float a = 0.f, b = 0.f;
    for (int r = chunk * 512; r < chunk * 512 + 512; r++) {
        float y = bf2f(hi[(size_t)r * C + col]) + bf2f(lo[(size_t)r * C + col]);
        a += y;
        b += y * y;
    }
    s1[chunk * 512 + col] = a;
    s2[chunk * 512 + col] = b;
}

// ---------------- kernel 5: deterministic finalization, 1 block ----------------
__global__ __launch_bounds__(512) void k_final(
    const float* __restrict__ dv, const float* __restrict__ dt,
    const float* __restrict__ pev, const float* __restrict__ pet,
    const float* __restrict__ pcv, const float* __restrict__ pct,
    const float* __restrict__ s1, const float* __restrict__ s2,
    float* __restrict__ out)
{
    __shared__ float red[512];
    const int t = threadIdx.x;

    auto block_sum = [&](float v) -> float {
        red[t] = v;
        __syncthreads();
        for (int o = 256; o >= 1; o >>= 1) {
            if (t < o) red[t] += red[t + o];
            __syncthreads();
        }
        float r = red[0];
        __syncthreads();
        return r;
    };

    // nominator = logsumexp over 2N diagonal logits (10*d), fixed shift 10
    float nom_p = 0.f;
    for (int i = t; i < N; i += 512)
        nom_p += __expf(10.f * dv[i] - 10.f) + __expf(10.f * dt[i] - 10.f);
    float nominator = logf(block_sum(nom_p)) + 10.f;

    // per-row denominator + retrieval counts
    float sden = 0.f;
    float rv0 = 0, rv1 = 0, rv2 = 0, rv3 = 0;
    float rt0 = 0, rt1 = 0, rt2 = 0, rt3 = 0;
    for (int i = t; i < N; i += 512) {
        float se = 0.f;
        for (int cb = 0; cb < 32; cb++) se += pev[cb * N + i];
        for (int cb = 0; cb < 32; cb++) se += pet[cb * N + i];
        sden += logf(se) + 10.f;
        float pv = 0.f, pt = 0.f;
        for (int cb = 0; cb < 32; cb++) pv += pcv[cb * N + i];
        for (int cb = 0; cb < 32; cb++) pt += pct[cb * N + i];
        rv0 += (pv < 0.5f) ? 1.f : 0.f;
        rv1 += (pv < 4.5f) ? 1.f : 0.f;
        rv2 += (pv < 9.5f) ? 1.f : 0.f;
        rv3 += pv;
        rt0 += (pt < 0.5f) ? 1.f : 0.f;
        rt1 += (pt < 4.5f) ? 1.f : 0.f;
        rt2 += (pt < 9.5f) ? 1.f : 0.f;
        rt3 += pt;
    }
    float S   = block_sum(sden);
    float Rv0 = block_sum(rv0), Rv1 = block_sum(rv1), Rv2 = block_sum(rv2), Rv3 = block_sum(rv3);
    float Rt0 = block_sum(rt0), Rt1 = block_sum(rt1), Rt2 = block_sum(rt2), Rt3 = block_sum(rt3);

    // stds: mean over columns of per-column std (ddof=1)
    float stds[4];
    for (int m = 0; m < 4; m++) {
        float a = 0.f, b = 0.f;
        for (int c = 0; c < 8; c++) {
            a += s1[(m * 8 + c) * 512 + t];
            b += s2[(m * 8 + c) * 512 + t];
        }
        float var = (b - a * a * (1.f / N)) * (1.f / (N - 1));
        stds[m] = block_sum(sqrtf(fmaxf(var, 0.f))) * (1.f / 512.f);
    }

    if (t == 0) {
        const float invN = 1.f / N;
        out[0]  = S * invN - nominator;
        out[1]  = stds[0];
        out[2]  = stds[1];
        out[3]  = stds[2];
        out[4]  = stds[3];
        out[5]  = Rv0 * invN;
        out[6]  = Rv1 * invN;
        out[7]  = Rv2 * invN;
        out[8]  = Rv3 * invN;
        out[9]  = Rt0 * invN;
        out[10] = Rt1 * invN;
        out[11] = Rt2 * invN;
        out[12] = Rt3 * invN;
    }
}

extern "C" void kernel_launch(void* const* d_in, const int* in_sizes, int n_in,
                              void* d_out, int out_size, void* d_ws, size_t ws_size,
                              hipStream_t stream)
{
    const float* fin[4] = {(const float*)d_in[0], (const float*)d_in[1],
                           (const float*)d_in[2], (const float*)d_in[3]};
    char* p = (char*)d_ws;
    const size_t NE = (size_t)N * C;           // 2,097,152 elems
    __hip_bfloat16* hiA[4];
    __hip_bfloat16* loA[4];
    for (int m = 0; m < 4; m++) {
        hiA[m] = (__hip_bfloat16*)p; p += NE * 2;
        loA[m] = (__hip_bfloat16*)p; p += NE * 2;
    }
    float* dv  = (float*)p; p += N * 4;
    float* dt  = (float*)p; p += N * 4;
    float* pev = (float*)p; p += 32 * N * 4;
    float* pet = (float*)p; p += 32 * N * 4;
    float* pcv = (float*)p; p += 32 * N * 4;
    float* pct = (float*)p; p += 32 * N * 4;
    float* s1  = (float*)p; p += 4 * 8 * 512 * 4;
    float* s2  = (float*)p; p += 4 * 8 * 512 * 4;

    // 1. normalize + split (v, t, pv, pt)
    for (int m = 0; m < 4; m++)
        k_norm_split<<<dim3(N), 256, 0, stream>>>(fin[m], hiA[m], loA[m]);

    // 2. diagonals: dv = diag(vn . ptn^T), dt = diag(tn . pvn^T)
    k_diag<<<dim3(N / 4), 256, 0, stream>>>(hiA[0], loA[0], hiA[3], loA[3], dv);
    k_diag<<<dim3(N / 4), 256, 0, stream>>>(hiA[1], loA[1], hiA[2], loA[2], dt);

    // 3. fused GEMM + epilogue: sv = vn . ptn^T ; st = tn . pvn^T
    k_gemm<<<dim3(32, 32), 256, 0, stream>>>(hiA[0], loA[0], hiA[3], loA[3], dv, pev, pcv);
    k_gemm<<<dim3(32, 32), 256, 0, stream>>>(hiA[1], loA[1], hiA[2], loA[2], dt, pet, pct);

    // 4. std partials
    for (int m = 0; m < 4; m++)
        k_stdp<<<dim3(8), 512, 0, stream>>>(hiA[m], loA[m],
                                            s1 + m * 8 * 512, s2 + m * 8 * 512);

    // 5. finalize all 13 scalars
    k_final<<<dim3(1), 512, 0, stream>>>(dv, dt, pev, pet, pcv, pct, s1, s2, (float*)d_out);
}

// Round 2
// 338.935 us; speedup vs baseline: 1.3941x; 1.3941x over previous
//
#include <hip/hip_runtime.h>
#include <hip/hip_bf16.h>

#define N 4096
#define C 512

typedef __attribute__((ext_vector_type(8))) short bf16x8;
typedef __attribute__((ext_vector_type(4))) float f32x4;

__device__ inline float bf2f(__hip_bfloat16 h) { return __bfloat162float(h); }

__device__ inline void gload16(const void* g, void* l) {
    __builtin_amdgcn_global_load_lds(
        (__attribute__((address_space(1))) void*)(g),
        (__attribute__((address_space(3))) void*)(l),
        16, 0, 0);
}

// ---------------- kernel 1: row L2-normalize + bf16 hi/lo split ----------------
__global__ __launch_bounds__(256) void k_norm_split(
    const float* __restrict__ src,
    __hip_bfloat16* __restrict__ hi, __hip_bfloat16* __restrict__ lo)
{
    const int row = blockIdx.x;
    const int tid = threadIdx.x;
    const float2* r = (const float2*)(src + (size_t)row * C);
    float2 x = r[tid];                       // 256 threads * 2 = 512
    float ss = x.x * x.x + x.y * x.y;
    for (int o = 1; o < 64; o <<= 1) ss += __shfl_xor(ss, o);
    __shared__ float wsum[4];
    if ((tid & 63) == 0) wsum[tid >> 6] = ss;
    __syncthreads();
    float tot = wsum[0] + wsum[1] + wsum[2] + wsum[3];
    float nrm = sqrtf(tot);
    float scale = 1.0f / fmaxf(nrm, 1e-12f);
    float y0 = x.x * scale, y1 = x.y * scale;
    __hip_bfloat16 h0 = __float2bfloat16(y0);
    __hip_bfloat16 h1 = __float2bfloat16(y1);
    __hip_bfloat16 l0 = __float2bfloat16(y0 - bf2f(h0));
    __hip_bfloat16 l1 = __float2bfloat16(y1 - bf2f(h1));
    size_t base = (size_t)row * C + 2 * tid;
    hi[base] = h0; hi[base + 1] = h1;
    lo[base] = l0; lo[base + 1] = l1;
}

// ---------------- kernel 2: diagonal dots (split arithmetic) ----------------
__global__ __launch_bounds__(256) void k_diag(
    const __hip_bfloat16* __restrict__ ah, const __hip_bfloat16* __restrict__ al,
    const __hip_bfloat16* __restrict__ bh, const __hip_bfloat16* __restrict__ bl,
    float* __restrict__ dout)
{
    const int lane = threadIdx.x & 63;
    const int w = threadIdx.x >> 6;
    const int row = blockIdx.x * 4 + w;
    size_t base = (size_t)row * C;
    float s = 0.f;
    for (int j = lane; j < C; j += 64) {
        float xh = bf2f(ah[base + j]), xl = bf2f(al[base + j]);
        float yh = bf2f(bh[base + j]), yl = bf2f(bl[base + j]);
        s += xh * yh + xh * yl + xl * yh;
    }
    for (int o = 1; o < 64; o <<= 1) s += __shfl_xor(s, o);
    if (lane == 0) dout[row] = s;
}

// ---------------- kernel 3: fused split-GEMM + epilogue ----------------
// C-tile 128x128, BK=32, 4 waves (2x2), 3 MFMA per frag pair (hi*hi+hi*lo+lo*hi).
// Epilogue: per-row sum of exp(10s-10) and count(s > diag, col!=row),
// written as partials [colblock][row].
__global__ __launch_bounds__(256) void k_gemm(
    const __hip_bfloat16* __restrict__ Ah, const __hip_bfloat16* __restrict__ Al,
    const __hip_bfloat16* __restrict__ Bh, const __hip_bfloat16* __restrict__ Bl,
    const float* __restrict__ diag,
    float* __restrict__ pe, float* __restrict__ pc)
{
    __shared__ __align__(16) __hip_bfloat16 sA[2][128][32];
    __shared__ __align__(16) __hip_bfloat16 sB[2][128][32];
    __shared__ float sdiag[128];
    __shared__ float sred[128][2][2];

    const int tid = threadIdx.x;
    const int lane = tid & 63;
    const int w = tid >> 6;
    const int wy = w >> 1, wx = w & 1;
    const int bm = blockIdx.x * 128;
    const int bn = blockIdx.y * 128;

    if (tid < 128) sdiag[tid] = diag[bm + tid];

    f32x4 acc[4][4];
    for (int i = 0; i < 4; i++)
        for (int j = 0; j < 4; j++)
            acc[i][j] = (f32x4){0.f, 0.f, 0.f, 0.f};

    const int srow = lane >> 2;        // 0..15
    const int scol = (lane & 3) * 8;   // bf16 elems
    const int fr = lane & 15;
    const int fq = (lane >> 4) * 8;

    for (int k0 = 0; k0 < C; k0 += 32) {
        // stage 4 tiles: A hi/lo (rows bm..), B hi/lo (rows bn..)
        for (int half = 0; half < 2; half++) {
            int rr = w * 16 + half * 64 + srow;
            size_t ga = (size_t)(bm + rr) * C + k0 + scol;
            size_t gb = (size_t)(bn + rr) * C + k0 + scol;
            gload16(Ah + ga, &sA[0][rr][scol]);
            gload16(Al + ga, &sA[1][rr][scol]);
            gload16(Bh + gb, &sB[0][rr][scol]);
            gload16(Bl + gb, &sB[1][rr][scol]);
        }
        __syncthreads();

        bf16x8 a_h[4], a_l[4], b_h[4], b_l[4];
        for (int i = 0; i < 4; i++) {
            a_h[i] = *(const bf16x8*)&sA[0][wy * 64 + i * 16 + fr][fq];
            a_l[i] = *(const bf16x8*)&sA[1][wy * 64 + i * 16 + fr][fq];
            b_h[i] = *(const bf16x8*)&sB[0][wx * 64 + i * 16 + fr][fq];
            b_l[i] = *(const bf16x8*)&sB[1][wx * 64 + i * 16 + fr][fq];
        }
        for (int i = 0; i < 4; i++)
            for (int j = 0; j < 4; j++) {
                acc[i][j] = __builtin_amdgcn_mfma_f32_16x16x32_bf16(a_h[i], b_h[j], acc[i][j], 0, 0, 0);
                acc[i][j] = __builtin_amdgcn_mfma_f32_16x16x32_bf16(a_h[i], b_l[j], acc[i][j], 0, 0, 0);
                acc[i][j] = __builtin_amdgcn_mfma_f32_16x16x32_bf16(a_l[i], b_h[j], acc[i][j], 0, 0, 0);
            }
        __syncthreads();
    }

    // epilogue: C/D layout row=(lane>>4)*4+reg, col=lane&15
    const int quad = lane >> 4;
    for (int i = 0; i < 4; i++) {
        for (int reg = 0; reg < 4; reg++) {
            int rloc = wy * 64 + i * 16 + quad * 4 + reg;
            int grow = bm + rloc;
            float d = sdiag[rloc];
            float e = 0.f, c = 0.f;
            for (int j = 0; j < 4; j++) {
                float s = acc[i][j][reg];
                int gcol = bn + wx * 64 + j * 16 + fr;
                e += __expf(10.f * s - 10.f);
                if (s > d && gcol != grow) c += 1.f;
            }
            for (int o = 1; o < 16; o <<= 1) {
                e += __shfl_xor(e, o);
                c += __shfl_xor(c, o);
            }
            if (fr == 0) { sred[rloc][wx][0] = e; sred[rloc][wx][1] = c; }
        }
    }
    __syncthreads();
    if (tid < 128) {
        pe[(size_t)blockIdx.y * N + bm + tid] = sred[tid][0][0] + sred[tid][1][0];
        pc[(size_t)blockIdx.y * N + bm + tid] = sred[tid][0][1] + sred[tid][1][1];
    }
}

// ---------------- kernel 4: per-column sum / sumsq partials (512 rows/chunk) ----------------
__global__ __launch_bounds__(512) void k_stdp(
    const __hip_bfloat16* __restrict__ hi, const __hip_bfloat16* __restrict__ lo,
    float* __restrict__ s1, float* __restrict__ s2)
{
    const int col = threadIdx.x;
    const int chunk = blockIdx.x;
    float a = 0.f, b = 0.f;
    for (int r = chunk * 512; r < chunk * 512 + 512; r++) {
        float y = bf2f(hi[(size_t)r * C + col]) + bf2f(lo[(size_t)r * C + col]);
        a += y;
        b += y * y;
    }
    s1[chunk * 512 + col] = a;
    s2[chunk * 512 + col] = b;
}

// ---------------- kernel 5a: parallel row reduction (16 blocks x 256 threads) ----
// Each thread owns one row: sums its 32+32 exp partials and count partials,
// computes log-denominator, rank indicators, nominator exp term; block-reduces
// 10 scalars -> partials[block][10].
__global__ __launch_bounds__(256) void k_rowred(
    const float* __restrict__ dv, const float* __restrict__ dt,
    const float* __restrict__ pev, const float* __restrict__ pet,
    const float* __restrict__ pcv, const float* __restrict__ pct,
    float* __restrict__ partials)
{
    const int t = threadIdx.x;
    const int row = blockIdx.x * 256 + t;

    float se = 0.f;
    for (int cb = 0; cb < 32; cb++) se += pev[(size_t)cb * N + row];
    for (int cb = 0; cb < 32; cb++) se += pet[(size_t)cb * N + row];
    float pv = 0.f, pt = 0.f;
    for (int cb = 0; cb < 32; cb++) pv += pcv[(size_t)cb * N + row];
    for (int cb = 0; cb < 32; cb++) pt += pct[(size_t)cb * N + row];

    float vals[10];
    vals[0] = logf(se) + 10.f;                       // denominator term
    vals[1] = (pv < 0.5f) ? 1.f : 0.f;
    vals[2] = (pv < 4.5f) ? 1.f : 0.f;
    vals[3] = (pv < 9.5f) ? 1.f : 0.f;
    vals[4] = pv;
    vals[5] = (pt < 0.5f) ? 1.f : 0.f;
    vals[6] = (pt < 4.5f) ? 1.f : 0.f;
    vals[7] = (pt < 9.5f) ? 1.f : 0.f;
    vals[8] = pt;
    vals[9] = __expf(10.f * dv[row] - 10.f) + __expf(10.f * dt[row] - 10.f); // nominator part

    __shared__ float wred[4][10];
    const int lane = t & 63, wv = t >> 6;
    for (int k = 0; k < 10; k++) {
        float v = vals[k];
        for (int o = 1; o < 64; o <<= 1) v += __shfl_xor(v, o);
        if (lane == 0) wred[wv][k] = v;
    }
    __syncthreads();
    if (t < 10) {
        partials[(size_t)blockIdx.x * 10 + t] =
            wred[0][t] + wred[1][t] + wred[2][t] + wred[3][t];
    }
}

// ---------------- kernel 5b: per-column std, one block per matrix --------------
__global__ __launch_bounds__(512) void k_colstd(
    const float* __restrict__ s1, const float* __restrict__ s2,
    float* __restrict__ stds)
{
    const int t = threadIdx.x;       // column
    const int m = blockIdx.x;        // matrix
    float a = 0.f, b = 0.f;
    for (int c = 0; c < 8; c++) {
        a += s1[((size_t)m * 8 + c) * 512 + t];
        b += s2[((size_t)m * 8 + c) * 512 + t];
    }
    float var = (b - a * a * (1.f / N)) * (1.f / (N - 1));
    float sd = sqrtf(fmaxf(var, 0.f));

    __shared__ float wred[8];
    const int lane = t & 63, wv = t >> 6;
    float v = sd;
    for (int o = 1; o < 64; o <<= 1) v += __shfl_xor(v, o);
    if (lane == 0) wred[wv] = v;
    __syncthreads();
    if (t == 0) {
        float s = 0.f;
        for (int i = 0; i < 8; i++) s += wred[i];
        stds[m] = s * (1.f / 512.f);
    }
}

// ---------------- kernel 5c: tiny final combine (reads ~700 B) -----------------
__global__ __launch_bounds__(64) void k_final2(
    const float* __restrict__ partials,   // [16][10]
    const float* __restrict__ stds,       // [4]
    float* __restrict__ out)
{
    const int lane = threadIdx.x;
    float v = 0.f;
    if (lane < 10) {
        for (int b = 0; b < 16; b++) v += partials[b * 10 + lane];
    }
    // v now holds, per lane k<10, the global sum of value k.
    __shared__ float g[10];
    if (lane < 10) g[lane] = v;
    __syncthreads();
    if (lane == 0) {
        const float invN = 1.f / N;
        float nominator = logf(g[9]) + 10.f;
        out[0]  = g[0] * invN - nominator;
        out[1]  = stds[0];
        out[2]  = stds[1];
        out[3]  = stds[2];
        out[4]  = stds[3];
        out[5]  = g[1] * invN;
        out[6]  = g[2] * invN;
        out[7]  = g[3] * invN;
        out[8]  = g[4] * invN;
        out[9]  = g[5] * invN;
        out[10] = g[6] * invN;
        out[11] = g[7] * invN;
        out[12] = g[8] * invN;
    }
}

extern "C" void kernel_launch(void* const* d_in, const int* in_sizes, int n_in,
                              void* d_out, int out_size, void* d_ws, size_t ws_size,
                              hipStream_t stream)
{
    const float* fin[4] = {(const float*)d_in[0], (const float*)d_in[1],
                           (const float*)d_in[2], (const float*)d_in[3]};
    char* p = (char*)d_ws;
    const size_t NE = (size_t)N * C;           // 2,097,152 elems
    __hip_bfloat16* hiA[4];
    __hip_bfloat16* loA[4];
    for (int m = 0; m < 4; m++) {
        hiA[m] = (__hip_bfloat16*)p; p += NE * 2;
        loA[m] = (__hip_bfloat16*)p; p += NE * 2;
    }
    float* dv  = (float*)p; p += N * 4;
    float* dt  = (float*)p; p += N * 4;
    float* pev = (float*)p; p += 32 * N * 4;
    float* pet = (float*)p; p += 32 * N * 4;
    float* pcv = (float*)p; p += 32 * N * 4;
    float* pct = (float*)p; p += 32 * N * 4;
    float* s1  = (float*)p; p += 4 * 8 * 512 * 4;
    float* s2  = (float*)p; p += 4 * 8 * 512 * 4;
    float* partials = (float*)p; p += 16 * 10 * 4;
    float* stds = (float*)p; p += 4 * 4;

    // 1. normalize + split (v, t, pv, pt)
    for (int m = 0; m < 4; m++)
        k_norm_split<<<dim3(N), 256, 0, stream>>>(fin[m], hiA[m], loA[m]);

    // 2. diagonals: dv = diag(vn . ptn^T), dt = diag(tn . pvn^T)
    k_diag<<<dim3(N / 4), 256, 0, stream>>>(hiA[0], loA[0], hiA[3], loA[3], dv);
    k_diag<<<dim3(N / 4), 256, 0, stream>>>(hiA[1], loA[1], hiA[2], loA[2], dt);

    // 3. fused GEMM + epilogue: sv = vn . ptn^T ; st = tn . pvn^T
    k_gemm<<<dim3(32, 32), 256, 0, stream>>>(hiA[0], loA[0], hiA[3], loA[3], dv, pev, pcv);
    k_gemm<<<dim3(32, 32), 256, 0, stream>>>(hiA[1], loA[1], hiA[2], loA[2], dt, pet, pct);

    // 4. std partials
    for (int m = 0; m < 4; m++)
        k_stdp<<<dim3(8), 512, 0, stream>>>(hiA[m], loA[m],
                                            s1 + m * 8 * 512, s2 + m * 8 * 512);

    // 5. parallel finalization
    k_rowred<<<dim3(16), 256, 0, stream>>>(dv, dt, pev, pet, pcv, pct, partials);
    k_colstd<<<dim3(4), 512, 0, stream>>>(s1, s2, stds);
    k_final2<<<dim3(1), 64, 0, stream>>>(partials, stds, (float*)d_out);
}

// Round 3
// 223.485 us; speedup vs baseline: 2.1143x; 1.5166x over previous
//
#include <hip/hip_runtime.h>
#include <hip/hip_bf16.h>

#define N 4096
#define C 512

typedef __attribute__((ext_vector_type(8))) short bf16x8;
typedef __attribute__((ext_vector_type(8))) short s16x8;
typedef __attribute__((ext_vector_type(4))) float f32x4;

__device__ inline float bf2f(__hip_bfloat16 h) { return __bfloat162float(h); }
__device__ inline float bfbits2f(unsigned short b) {
    union { unsigned u; float f; } c; c.u = ((unsigned)b) << 16; return c.f;
}

__device__ inline void gload16(const void* g, void* l) {
    __builtin_amdgcn_global_load_lds(
        (__attribute__((address_space(1))) void*)(g),
        (__attribute__((address_space(3))) void*)(l),
        16, 0, 0);
}

// ---------------- kernel 1: row L2-normalize + bf16 hi/lo split (all 4 mats) ---
__global__ __launch_bounds__(256) void k_norm_split(
    const float* __restrict__ s0, const float* __restrict__ s1f,
    const float* __restrict__ s2f, const float* __restrict__ s3,
    __hip_bfloat16* __restrict__ ws_hi0, long mat_stride) // stride in bf16 elems
{
    const int m = blockIdx.x >> 12;          // 4096 rows per matrix
    const int row = blockIdx.x & 4095;
    const int tid = threadIdx.x;
    const float* src = (m == 0) ? s0 : (m == 1) ? s1f : (m == 2) ? s2f : s3;
    __hip_bfloat16* hi = ws_hi0 + (long)m * mat_stride;
    __hip_bfloat16* lo = hi + (long)N * C;

    const float2* r = (const float2*)(src + (size_t)row * C);
    float2 x = r[tid];                       // 256 threads * 2 = 512
    float ss = x.x * x.x + x.y * x.y;
    for (int o = 1; o < 64; o <<= 1) ss += __shfl_xor(ss, o);
    __shared__ float wsum[4];
    if ((tid & 63) == 0) wsum[tid >> 6] = ss;
    __syncthreads();
    float tot = wsum[0] + wsum[1] + wsum[2] + wsum[3];
    float scale = 1.0f / fmaxf(sqrtf(tot), 1e-12f);
    float y0 = x.x * scale, y1 = x.y * scale;
    __hip_bfloat16 h0 = __float2bfloat16(y0);
    __hip_bfloat16 h1 = __float2bfloat16(y1);
    __hip_bfloat16 l0 = __float2bfloat16(y0 - bf2f(h0));
    __hip_bfloat16 l1 = __float2bfloat16(y1 - bf2f(h1));
    size_t base = (size_t)row * C + 2 * tid;
    hi[base] = h0; hi[base + 1] = h1;
    lo[base] = l0; lo[base + 1] = l1;
}

// ---------------- kernel 2: both diagonals, vectorized ----------------
// blockIdx.y==0: dv = diag(vn.ptn^T); ==1: dt = diag(tn.pvn^T).
__global__ __launch_bounds__(256) void k_diag(
    const unsigned short* __restrict__ h0, const unsigned short* __restrict__ l0,
    const unsigned short* __restrict__ h1, const unsigned short* __restrict__ l1,
    const unsigned short* __restrict__ h2, const unsigned short* __restrict__ l2,
    const unsigned short* __restrict__ h3, const unsigned short* __restrict__ l3,
    float* __restrict__ dv, float* __restrict__ dt)
{
    const int lane = threadIdx.x & 63;
    const int w = threadIdx.x >> 6;
    const int row = blockIdx.x * 4 + w;
    const int z = blockIdx.y;
    const unsigned short* ah = z ? h1 : h0;
    const unsigned short* al = z ? l1 : l0;
    const unsigned short* bh = z ? h2 : h3;
    const unsigned short* bl = z ? l2 : l3;
    float* dout = z ? dt : dv;

    size_t base = (size_t)row * C + lane * 8;
    s16x8 xh = *(const s16x8*)(ah + base);
    s16x8 xl = *(const s16x8*)(al + base);
    s16x8 yh = *(const s16x8*)(bh + base);
    s16x8 yl = *(const s16x8*)(bl + base);
    float s = 0.f;
    for (int e = 0; e < 8; e++) {
        float a = bfbits2f((unsigned short)xh[e]);
        float b = bfbits2f((unsigned short)xl[e]);
        float c = bfbits2f((unsigned short)yh[e]);
        float d = bfbits2f((unsigned short)yl[e]);
        s += a * c + a * d + b * c;
    }
    for (int o = 1; o < 64; o <<= 1) s += __shfl_xor(s, o);
    if (lane == 0) dout[row] = s;
}

// ---------------- kernel 3: fused split-GEMM + epilogue (both GEMMs, z) -------
// C-tile 128x128, BK=32, 4 waves (2x2), 3 MFMA per frag pair (hi*hi+hi*lo+lo*hi).
// Epilogue partials row-major: pe[row*32 + colblock].
__global__ __launch_bounds__(256) void k_gemm(
    const __hip_bfloat16* __restrict__ h0, const __hip_bfloat16* __restrict__ l0,
    const __hip_bfloat16* __restrict__ h1, const __hip_bfloat16* __restrict__ l1,
    const __hip_bfloat16* __restrict__ h2, const __hip_bfloat16* __restrict__ l2,
    const __hip_bfloat16* __restrict__ h3, const __hip_bfloat16* __restrict__ l3,
    const float* __restrict__ dv, const float* __restrict__ dt,
    float* __restrict__ pev, float* __restrict__ pet,
    float* __restrict__ pcv, float* __restrict__ pct)
{
    __shared__ __align__(16) __hip_bfloat16 sA[2][128][32];
    __shared__ __align__(16) __hip_bfloat16 sB[2][128][32];
    __shared__ float sdiag[128];
    __shared__ float sred[128][2][2];

    const int z = blockIdx.z;
    const __hip_bfloat16* Ah = z ? h1 : h0;
    const __hip_bfloat16* Al = z ? l1 : l0;
    const __hip_bfloat16* Bh = z ? h2 : h3;
    const __hip_bfloat16* Bl = z ? l2 : l3;
    const float* diag = z ? dt : dv;
    float* pe = z ? pet : pev;
    float* pc = z ? pct : pcv;

    const int tid = threadIdx.x;
    const int lane = tid & 63;
    const int w = tid >> 6;
    const int wy = w >> 1, wx = w & 1;
    const int bm = blockIdx.x * 128;
    const int bn = blockIdx.y * 128;

    if (tid < 128) sdiag[tid] = diag[bm + tid];

    f32x4 acc[4][4];
    for (int i = 0; i < 4; i++)
        for (int j = 0; j < 4; j++)
            acc[i][j] = (f32x4){0.f, 0.f, 0.f, 0.f};

    const int srow = lane >> 2;        // 0..15
    const int scol = (lane & 3) * 8;   // bf16 elems
    const int fr = lane & 15;
    const int fq = (lane >> 4) * 8;

    for (int k0 = 0; k0 < C; k0 += 32) {
        for (int half = 0; half < 2; half++) {
            int rr = w * 16 + half * 64 + srow;
            size_t ga = (size_t)(bm + rr) * C + k0 + scol;
            size_t gb = (size_t)(bn + rr) * C + k0 + scol;
            gload16(Ah + ga, &sA[0][rr][scol]);
            gload16(Al + ga, &sA[1][rr][scol]);
            gload16(Bh + gb, &sB[0][rr][scol]);
            gload16(Bl + gb, &sB[1][rr][scol]);
        }
        __syncthreads();

        bf16x8 a_h[4], a_l[4], b_h[4], b_l[4];
        for (int i = 0; i < 4; i++) {
            a_h[i] = *(const bf16x8*)&sA[0][wy * 64 + i * 16 + fr][fq];
            a_l[i] = *(const bf16x8*)&sA[1][wy * 64 + i * 16 + fr][fq];
            b_h[i] = *(const bf16x8*)&sB[0][wx * 64 + i * 16 + fr][fq];
            b_l[i] = *(const bf16x8*)&sB[1][wx * 64 + i * 16 + fr][fq];
        }
        for (int i = 0; i < 4; i++)
            for (int j = 0; j < 4; j++) {
                acc[i][j] = __builtin_amdgcn_mfma_f32_16x16x32_bf16(a_h[i], b_h[j], acc[i][j], 0, 0, 0);
                acc[i][j] = __builtin_amdgcn_mfma_f32_16x16x32_bf16(a_h[i], b_l[j], acc[i][j], 0, 0, 0);
                acc[i][j] = __builtin_amdgcn_mfma_f32_16x16x32_bf16(a_l[i], b_h[j], acc[i][j], 0, 0, 0);
            }
        __syncthreads();
    }

    // epilogue: C/D layout row=(lane>>4)*4+reg, col=lane&15
    const int quad = lane >> 4;
    for (int i = 0; i < 4; i++) {
        for (int reg = 0; reg < 4; reg++) {
            int rloc = wy * 64 + i * 16 + quad * 4 + reg;
            int grow = bm + rloc;
            float d = sdiag[rloc];
            float e = 0.f, c = 0.f;
            for (int j = 0; j < 4; j++) {
                float s = acc[i][j][reg];
                int gcol = bn + wx * 64 + j * 16 + fr;
                e += __expf(10.f * s - 10.f);
                if (s > d && gcol != grow) c += 1.f;
            }
            for (int o = 1; o < 16; o <<= 1) {
                e += __shfl_xor(e, o);
                c += __shfl_xor(c, o);
            }
            if (fr == 0) { sred[rloc][wx][0] = e; sred[rloc][wx][1] = c; }
        }
    }
    __syncthreads();
    if (tid < 128) {
        size_t idx = (size_t)(bm + tid) * 32 + blockIdx.y;
        pe[idx] = sred[tid][0][0] + sred[tid][1][0];
        pc[idx] = sred[tid][0][1] + sred[tid][1][1];
    }
}

// ---------------- kernel 4: per-column sum/sumsq partials, 64 chunks x 4 mats --
__global__ __launch_bounds__(512) void k_stdp(
    const __hip_bfloat16* __restrict__ ws_hi0, long mat_stride,
    float* __restrict__ s1, float* __restrict__ s2)
{
    const int col = threadIdx.x;
    const int chunk = blockIdx.x;    // 0..63, 64 rows each
    const int m = blockIdx.y;        // matrix
    const __hip_bfloat16* hi = ws_hi0 + (long)m * mat_stride;
    const __hip_bfloat16* lo = hi + (long)N * C;
    float a = 0.f, b = 0.f;
    for (int r = chunk * 64; r < chunk * 64 + 64; r++) {
        float y = bf2f(hi[(size_t)r * C + col]) + bf2f(lo[(size_t)r * C + col]);
        a += y;
        b += y * y;
    }
    size_t idx = ((size_t)m * 64 + chunk) * 512 + col;
    s1[idx] = a;
    s2[idx] = b;
}

// ---------------- kernel 5a: row reduction, 64 blocks x 64 threads -------------
__global__ __launch_bounds__(64) void k_rowred(
    const float* __restrict__ dv, const float* __restrict__ dt,
    const float* __restrict__ pev, const float* __restrict__ pet,
    const float* __restrict__ pcv, const float* __restrict__ pct,
    float* __restrict__ partials)
{
    const int lane = threadIdx.x;
    const int row = blockIdx.x * 64 + lane;

    float se = 0.f, pv = 0.f, pt = 0.f;
    for (int cb = 0; cb < 32; cb++) {
        se += pev[(size_t)row * 32 + cb] + pet[(size_t)row * 32 + cb];
        pv += pcv[(size_t)row * 32 + cb];
        pt += pct[(size_t)row * 32 + cb];
    }

    float vals[10];
    vals[0] = logf(se) + 10.f;                       // denominator term
    vals[1] = (pv < 0.5f) ? 1.f : 0.f;
    vals[2] = (pv < 4.5f) ? 1.f : 0.f;
    vals[3] = (pv < 9.5f) ? 1.f : 0.f;
    vals[4] = pv;
    vals[5] = (pt < 0.5f) ? 1.f : 0.f;
    vals[6] = (pt < 4.5f) ? 1.f : 0.f;
    vals[7] = (pt < 9.5f) ? 1.f : 0.f;
    vals[8] = pt;
    vals[9] = __expf(10.f * dv[row] - 10.f) + __expf(10.f * dt[row] - 10.f);

    for (int k = 0; k < 10; k++) {
        float v = vals[k];
        for (int o = 1; o < 64; o <<= 1) v += __shfl_xor(v, o);
        if (lane == k) partials[(size_t)blockIdx.x * 10 + k] = v;
    }
}

// ---------------- kernel 5b: per-column std, 32 blocks x 64 threads ------------
// block b: matrix m=b>>3, columns (b&7)*64 .. +63; sums 64 chunks, wave-reduces
// the 64 stds -> stdpart[b].
__global__ __launch_bounds__(64) void k_colstd(
    const float* __restrict__ s1, const float* __restrict__ s2,
    float* __restrict__ stdpart)
{
    const int lane = threadIdx.x;
    const int m = blockIdx.x >> 3;
    const int col = (blockIdx.x & 7) * 64 + lane;
    float a = 0.f, b = 0.f;
    for (int ch = 0; ch < 64; ch++) {
        size_t idx = ((size_t)m * 64 + ch) * 512 + col;
        a += s1[idx];
        b += s2[idx];
    }
    float var = (b - a * a * (1.f / N)) * (1.f / (N - 1));
    float sd = sqrtf(fmaxf(var, 0.f));
    for (int o = 1; o < 64; o <<= 1) sd += __shfl_xor(sd, o);
    if (lane == 0) stdpart[blockIdx.x] = sd;
}

// ---------------- kernel 5c: tiny final combine --------------------------------
__global__ __launch_bounds__(64) void k_final2(
    const float* __restrict__ partials,   // [64][10]
    const float* __restrict__ stdpart,    // [32] (8 per matrix)
    float* __restrict__ out)
{
    const int lane = threadIdx.x;
    float v = 0.f;
    if (lane < 10) {
        for (int b = 0; b < 64; b++) v += partials[b * 10 + lane];
    }
    __shared__ float g[10];
    __shared__ float stds[4];
    if (lane < 10) g[lane] = v;
    if (lane < 4) {
        float s = 0.f;
        for (int i = 0; i < 8; i++) s += stdpart[lane * 8 + i];
        stds[lane] = s * (1.f / 512.f);
    }
    __syncthreads();
    if (lane == 0) {
        const float invN = 1.f / N;
        float nominator = logf(g[9]) + 10.f;
        out[0]  = g[0] * invN - nominator;
        out[1]  = stds[0];
        out[2]  = stds[1];
        out[3]  = stds[2];
        out[4]  = stds[3];
        out[5]  = g[1] * invN;
        out[6]  = g[2] * invN;
        out[7]  = g[3] * invN;
        out[8]  = g[4] * invN;
        out[9]  = g[5] * invN;
        out[10] = g[6] * invN;
        out[11] = g[7] * invN;
        out[12] = g[8] * invN;
    }
}

extern "C" void kernel_launch(void* const* d_in, const int* in_sizes, int n_in,
                              void* d_out, int out_size, void* d_ws, size_t ws_size,
                              hipStream_t stream)
{
    char* p = (char*)d_ws;
    const size_t NE = (size_t)N * C;           // 2,097,152 elems
    const long mat_stride = 2 * NE;            // hi + lo, in bf16 elems
    __hip_bfloat16* hiA[4];
    __hip_bfloat16* loA[4];
    for (int m = 0; m < 4; m++) {
        hiA[m] = (__hip_bfloat16*)p; p += NE * 2;
        loA[m] = (__hip_bfloat16*)p; p += NE * 2;
    }
    float* dv  = (float*)p; p += N * 4;
    float* dt  = (float*)p; p += N * 4;
    float* pev = (float*)p; p += 32 * N * 4;
    float* pet = (float*)p; p += 32 * N * 4;
    float* pcv = (float*)p; p += 32 * N * 4;
    float* pct = (float*)p; p += 32 * N * 4;
    float* s1  = (float*)p; p += 4 * 64 * 512 * 4;
    float* s2  = (float*)p; p += 4 * 64 * 512 * 4;
    float* partials = (float*)p; p += 64 * 10 * 4;
    float* stdpart  = (float*)p; p += 32 * 4;

    // 1. normalize + split (all 4 matrices, one dispatch)
    k_norm_split<<<dim3(4 * N), 256, 0, stream>>>(
        (const float*)d_in[0], (const float*)d_in[1],
        (const float*)d_in[2], (const float*)d_in[3],
        hiA[0], mat_stride);

    // 2. both diagonals in one dispatch
    k_diag<<<dim3(N / 4, 2), 256, 0, stream>>>(
        (const unsigned short*)hiA[0], (const unsigned short*)loA[0],
        (const unsigned short*)hiA[1], (const unsigned short*)loA[1],
        (const unsigned short*)hiA[2], (const unsigned short*)loA[2],
        (const unsigned short*)hiA[3], (const unsigned short*)loA[3],
        dv, dt);

    // 3. both fused GEMMs in one dispatch (z selects)
    k_gemm<<<dim3(32, 32, 2), 256, 0, stream>>>(
        hiA[0], loA[0], hiA[1], loA[1], hiA[2], loA[2], hiA[3], loA[3],
        dv, dt, pev, pet, pcv, pct);

    // 4. std partials: 64 chunks x 4 matrices
    k_stdp<<<dim3(64, 4), 512, 0, stream>>>(hiA[0], mat_stride, s1, s2);

    // 5. parallel finalization
    k_rowred<<<dim3(64), 64, 0, stream>>>(dv, dt, pev, pet, pcv, pct, partials);
    k_colstd<<<dim3(32), 64, 0, stream>>>(s1, s2, stdpart);
    k_final2<<<dim3(1), 64, 0, stream>>>(partials, stdpart, (float*)d_out);
}